// Round 6
// baseline (258.704 us; speedup 1.0000x reference)
//
#include <hip/hip_runtime.h>

#define HID 128
#define LN_EPS 1e-5f
#define LDSW 136  // LDS row stride in shorts (272 B): +4 banks/row, kills 16-way conflict

typedef __attribute__((ext_vector_type(8))) short bf16x8;
typedef __attribute__((ext_vector_type(4))) float f32x4;

static __device__ __forceinline__ unsigned short f2bf(float f) {
  unsigned int x = __float_as_uint(f);
  x += 0x7fffu + ((x >> 16) & 1u);  // RNE
  return (unsigned short)(x >> 16);
}
static __device__ __forceinline__ float bflo(unsigned int u) { return __uint_as_float(u << 16); }
static __device__ __forceinline__ float bfhi(unsigned int u) { return __uint_as_float(u & 0xffff0000u); }

// ---------------- CSR build (counting sort by dst) ----------------
__global__ __launch_bounds__(256) void k_count(const int* __restrict__ ei,
                                               int* __restrict__ counts, int nE) {
  const int e = blockIdx.x * 256 + threadIdx.x;
  if (e >= nE) return;
  atomicAdd(&counts[ei[nE + e]], 1);
}

__global__ __launch_bounds__(256) void k_scan1(const int* __restrict__ counts,
                                               int* __restrict__ offsets,
                                               int* __restrict__ bsum, int n) {
  __shared__ int sm[256];
  const int t = threadIdx.x;
  const int i = blockIdx.x * 256 + t;
  const int v = (i < n) ? counts[i] : 0;
  int incl = v;
  sm[t] = incl;
  __syncthreads();
#pragma unroll
  for (int off = 1; off < 256; off <<= 1) {
    const int other = (t >= off) ? sm[t - off] : 0;
    __syncthreads();
    incl += other;
    sm[t] = incl;
    __syncthreads();
  }
  if (i < n) offsets[i] = incl - v;
  if (t == 255) bsum[blockIdx.x] = incl;
}

__global__ __launch_bounds__(256) void k_scan2(const int* __restrict__ bsum,
                                               int* __restrict__ ebase,
                                               int* __restrict__ offsets,
                                               int nb, int n) {
  __shared__ int sm[256];
  const int t = threadIdx.x;
  const int v = (t < nb) ? bsum[t] : 0;
  int incl = v;
  sm[t] = incl;
  __syncthreads();
#pragma unroll
  for (int off = 1; off < 256; off <<= 1) {
    const int other = (t >= off) ? sm[t - off] : 0;
    __syncthreads();
    incl += other;
    sm[t] = incl;
    __syncthreads();
  }
  if (t < nb) ebase[t] = incl - v;
  if (t == 255) offsets[n] = incl;
}

__global__ __launch_bounds__(256) void k_scan3(int* __restrict__ offsets,
                                               int* __restrict__ cursors,
                                               const int* __restrict__ ebase, int n) {
  const int i = blockIdx.x * 256 + threadIdx.x;
  if (i >= n) return;
  const int o = offsets[i] + ebase[blockIdx.x];
  offsets[i] = o;
  cursors[i] = o;
}

__global__ __launch_bounds__(256) void k_bucket(const int* __restrict__ ei,
                                                int* __restrict__ cursors,
                                                int* __restrict__ esrc, int nE) {
  const int e = blockIdx.x * 256 + threadIdx.x;
  if (e >= nE) return;
  const int s = ei[e];
  const int d = ei[nE + e];
  const int pos = atomicAdd(&cursors[d], 1);
  esrc[pos] = s;
}

// ---------------- f32 -> bf16 for h, W1, W2 in one launch ----------------
__global__ __launch_bounds__(256) void k_tobf3(const float* __restrict__ h,
                                               const float* __restrict__ w1,
                                               const float* __restrict__ w2,
                                               uint2* __restrict__ hb,
                                               uint2* __restrict__ w1b,
                                               uint2* __restrict__ w2b,
                                               int nh4, int nw4) {
  const int total = nh4 + 2 * nw4;
  const int stride = gridDim.x * 256;
  for (int i = blockIdx.x * 256 + threadIdx.x; i < total; i += stride) {
    const float* src;
    uint2* dst;
    int off;
    if (i < nh4) { src = h; dst = hb; off = i; }
    else if (i < nh4 + nw4) { src = w1; dst = w1b; off = i - nh4; }
    else { src = w2; dst = w2b; off = i - nh4 - nw4; }
    const float4 v = reinterpret_cast<const float4*>(src)[off];
    uint2 p;
    p.x = (unsigned)f2bf(v.x) | ((unsigned)f2bf(v.y) << 16);
    p.y = (unsigned)f2bf(v.z) | ((unsigned)f2bf(v.w) << 16);
    dst[off] = p;
  }
}

// ---------------- fused: gather -> GEMM1(relu) -> GEMM2 -> +h, LN, relu ----------------
// Block = 256 threads (4 waves) = 64 node-rows. LDS tile zt[64][LDSW] (17.4 KB).
// Phase 1: gather z rows (bf16) into LDS (8 passes x 8 nodes x 32 lanes). 1 barrier.
// Phase 2 (per wave, own 16 rows): A-frags <- LDS, B-frags <- W1 global (L1-hot),
//   32 MFMAs, bias+relu, y1 -> same LDS rows (wave-private; in-wave lgkmcnt ordering).
// Phase 3: A-frags <- LDS (y1), B <- W2, 32 MFMAs, bias + f32 h residual,
//   LN via 16-lane shfl_xor, relu, f32 out.
__global__ __launch_bounds__(256) void k_fused(const unsigned short* __restrict__ hbf,
                                               const int* __restrict__ offsets,
                                               const int* __restrict__ esrc,
                                               const float* __restrict__ eps,
                                               const unsigned short* __restrict__ w1,
                                               const unsigned short* __restrict__ w2,
                                               const float* __restrict__ b1,
                                               const float* __restrict__ b2,
                                               const float* __restrict__ h,
                                               const float* __restrict__ gamma,
                                               const float* __restrict__ beta,
                                               float* __restrict__ out, int nNodes) {
  __shared__ unsigned short zt[64][LDSW];
  const int t = threadIdx.x;
  const int tile64 = blockIdx.x * 64;
  const float c = 1.0f + eps[0];

  // ---- phase 1: gather ----
#pragma unroll
  for (int p = 0; p < 8; ++p) {
    const int r = p * 8 + (t >> 5);       // LDS row 0..63
    const int node = tile64 + r;
    const int col4 = (t & 31) * 4;
    if (node < nNodes) {
      const uint2 hv = *reinterpret_cast<const uint2*>(hbf + (size_t)node * HID + col4);
      float a0 = c * bflo(hv.x), a1 = c * bfhi(hv.x);
      float a2 = c * bflo(hv.y), a3 = c * bfhi(hv.y);
      const int beg = offsets[node], end = offsets[node + 1];
      int e = beg;
      for (; e + 1 < end; e += 2) {
        const int s0 = esrc[e], s1 = esrc[e + 1];
        const uint2 v0 = *reinterpret_cast<const uint2*>(hbf + (size_t)s0 * HID + col4);
        const uint2 v1 = *reinterpret_cast<const uint2*>(hbf + (size_t)s1 * HID + col4);
        a0 += bflo(v0.x) + bflo(v1.x);
        a1 += bfhi(v0.x) + bfhi(v1.x);
        a2 += bflo(v0.y) + bflo(v1.y);
        a3 += bfhi(v0.y) + bfhi(v1.y);
      }
      if (e < end) {
        const uint2 v0 = *reinterpret_cast<const uint2*>(hbf + (size_t)esrc[e] * HID + col4);
        a0 += bflo(v0.x); a1 += bfhi(v0.x); a2 += bflo(v0.y); a3 += bfhi(v0.y);
      }
      uint2 o;
      o.x = (unsigned)f2bf(a0) | ((unsigned)f2bf(a1) << 16);
      o.y = (unsigned)f2bf(a2) | ((unsigned)f2bf(a3) << 16);
      *reinterpret_cast<uint2*>(&zt[r][col4]) = o;
    }
  }
  __syncthreads();

  // ---- phases 2+3: per-wave 16-row tile ----
  const int l = t & 63;
  const int lr = l & 15;
  const int lq = l >> 4;
  const int row0w = (t >> 6) * 16;       // LDS row base of this wave
  const int grow0 = tile64 + row0w;      // global row base
  if (grow0 >= nNodes) return;           // nNodes % 16 == 0: tile all-or-nothing

  bf16x8 a[4];
#pragma unroll
  for (int ks = 0; ks < 4; ++ks)
    a[ks] = *reinterpret_cast<const bf16x8*>(&zt[row0w + lr][ks * 32 + lq * 8]);

  f32x4 acc[8];
#pragma unroll
  for (int nt = 0; nt < 8; ++nt) acc[nt] = (f32x4){0.f, 0.f, 0.f, 0.f};
#pragma unroll
  for (int nt = 0; nt < 8; ++nt) {
    const unsigned short* wb = w1 + (size_t)(nt * 16 + lr) * HID + lq * 8;
#pragma unroll
    for (int ks = 0; ks < 4; ++ks) {
      const bf16x8 b = *reinterpret_cast<const bf16x8*>(wb + ks * 32);
      acc[nt] = __builtin_amdgcn_mfma_f32_16x16x32_bf16(a[ks], b, acc[nt], 0, 0, 0);
    }
  }

  // y1 = relu(acc + b1) -> back into this wave's own LDS rows (C-layout: col=lr, row=lq*4+r)
#pragma unroll
  for (int nt = 0; nt < 8; ++nt) {
    const int cc = nt * 16 + lr;
    const float bs = b1[cc];
#pragma unroll
    for (int r = 0; r < 4; ++r)
      zt[row0w + lq * 4 + r][cc] = f2bf(fmaxf(acc[nt][r] + bs, 0.f));
  }

  bf16x8 a2[4];
#pragma unroll
  for (int ks = 0; ks < 4; ++ks)
    a2[ks] = *reinterpret_cast<const bf16x8*>(&zt[row0w + lr][ks * 32 + lq * 8]);

#pragma unroll
  for (int nt = 0; nt < 8; ++nt) acc[nt] = (f32x4){0.f, 0.f, 0.f, 0.f};
#pragma unroll
  for (int nt = 0; nt < 8; ++nt) {
    const unsigned short* wb = w2 + (size_t)(nt * 16 + lr) * HID + lq * 8;
#pragma unroll
    for (int ks = 0; ks < 4; ++ks) {
      const bf16x8 b = *reinterpret_cast<const bf16x8*>(wb + ks * 32);
      acc[nt] = __builtin_amdgcn_mfma_f32_16x16x32_bf16(a2[ks], b, acc[nt], 0, 0, 0);
    }
  }

  // bias + residual (f32 h)
#pragma unroll
  for (int nt = 0; nt < 8; ++nt) {
    const int cc = nt * 16 + lr;
    const float bs = b2[cc];
#pragma unroll
    for (int r = 0; r < 4; ++r) {
      const int row = grow0 + lq * 4 + r;
      acc[nt][r] += bs + h[(size_t)row * HID + cc];
    }
  }

  // LayerNorm per row (row spans the 16-lane group) + relu + store
  float mu_[4], rstd_[4];
#pragma unroll
  for (int r = 0; r < 4; ++r) {
    float s = 0.f, ss = 0.f;
#pragma unroll
    for (int nt = 0; nt < 8; ++nt) { const float v = acc[nt][r]; s += v; ss += v * v; }
#pragma unroll
    for (int m = 1; m < 16; m <<= 1) {
      s += __shfl_xor(s, m, 64);
      ss += __shfl_xor(ss, m, 64);
    }
    const float mu = s * (1.f / 128.f);
    const float var = ss * (1.f / 128.f) - mu * mu;
    mu_[r] = mu;
    rstd_[r] = rsqrtf(var + LN_EPS);
  }
#pragma unroll
  for (int nt = 0; nt < 8; ++nt) {
    const int cc = nt * 16 + lr;
    const float g = gamma[cc], be = beta[cc];
#pragma unroll
    for (int r = 0; r < 4; ++r) {
      const int row = grow0 + lq * 4 + r;
      const float o = (acc[nt][r] - mu_[r]) * rstd_[r] * g + be;
      out[(size_t)row * HID + cc] = fmaxf(o, 0.f);
    }
  }
}

extern "C" void kernel_launch(void* const* d_in, const int* in_sizes, int n_in,
                              void* d_out, int out_size, void* d_ws, size_t ws_size,
                              hipStream_t stream) {
  const float* h     = (const float*)d_in[0];
  const int*   ei    = (const int*)d_in[1];
  const float* W1    = (const float*)d_in[2];
  const float* b1    = (const float*)d_in[3];
  const float* W2    = (const float*)d_in[4];
  const float* b2    = (const float*)d_in[5];
  const float* eps   = (const float*)d_in[6];
  const float* gamma = (const float*)d_in[7];
  const float* beta  = (const float*)d_in[8];

  const int nNodes = in_sizes[0] / HID;     // 50000
  const int nE     = in_sizes[1] / 2;       // 640000
  const int nb     = (nNodes + 255) / 256;  // 196

  // ws layout (ints first, then 16B-aligned bf16 regions):
  int* counts  = (int*)d_ws;
  int* offsets = counts + nNodes;                 // @ 50000
  int* cursors = offsets + nNodes + 1;            // @ 100001
  int* bsum    = cursors + nNodes;                // @ 150001
  int* ebase   = bsum + nb;                       // @ 150197
  int* esrc    = counts + 150400;                 // @ 150400 (byte 601600, 16B-aligned)
  unsigned short* hbf  = (unsigned short*)(esrc + nE);   // byte 3,161,600 (16B-aligned)
  unsigned short* w1bf = hbf + (size_t)nNodes * HID;     // +12.8 MB
  unsigned short* w2bf = w1bf + HID * HID;               // +32 KB (total ~16 MB)

  hipMemsetAsync(counts, 0, (size_t)nNodes * sizeof(int), stream);

  const int eblocks = (nE + 255) / 256;
  k_tobf3<<<2048, 256, 0, stream>>>(h, W1, W2, (uint2*)hbf, (uint2*)w1bf, (uint2*)w2bf,
                                    nNodes * HID / 4, HID * HID / 4);
  k_count<<<eblocks, 256, 0, stream>>>(ei, counts, nE);
  k_scan1<<<nb, 256, 0, stream>>>(counts, offsets, bsum, nNodes);
  k_scan2<<<1, 256, 0, stream>>>(bsum, ebase, offsets, nb, nNodes);
  k_scan3<<<nb, 256, 0, stream>>>(offsets, cursors, ebase, nNodes);
  k_bucket<<<eblocks, 256, 0, stream>>>(ei, cursors, esrc, nE);

  const int fblocks = (nNodes + 63) / 64;   // 782
  k_fused<<<fblocks, 256, 0, stream>>>(hbf, offsets, esrc, eps, w1bf, w2bf,
                                       b1, b2, h, gamma, beta, (float*)d_out, nNodes);
}

// Round 8
// 247.791 us; speedup vs baseline: 1.0440x; 1.0440x over previous
//
#include <hip/hip_runtime.h>

#define HID 128
#define LN_EPS 1e-5f
#define LDSW 136  // LDS row stride in shorts (272 B) -> 2-way-only aliasing on b128 reads (free)

typedef __attribute__((ext_vector_type(8))) short bf16x8;
typedef __attribute__((ext_vector_type(4))) float f32x4;

static __device__ __forceinline__ unsigned short f2bf(float f) {
  unsigned int x = __float_as_uint(f);
  x += 0x7fffu + ((x >> 16) & 1u);  // RNE
  return (unsigned short)(x >> 16);
}
static __device__ __forceinline__ float bflo(unsigned int u) { return __uint_as_float(u << 16); }
static __device__ __forceinline__ float bfhi(unsigned int u) { return __uint_as_float(u & 0xffff0000u); }

// ---------------- CSR build (counting sort by dst) ----------------
__global__ __launch_bounds__(256) void k_count(const int* __restrict__ ei,
                                               int* __restrict__ counts, int nE) {
  const int e = blockIdx.x * 256 + threadIdx.x;
  if (e >= nE) return;
  atomicAdd(&counts[ei[nE + e]], 1);
}

__global__ __launch_bounds__(256) void k_scan1(const int* __restrict__ counts,
                                               int* __restrict__ offsets,
                                               int* __restrict__ bsum, int n) {
  __shared__ int sm[256];
  const int t = threadIdx.x;
  const int i = blockIdx.x * 256 + t;
  const int v = (i < n) ? counts[i] : 0;
  int incl = v;
  sm[t] = incl;
  __syncthreads();
#pragma unroll
  for (int off = 1; off < 256; off <<= 1) {
    const int other = (t >= off) ? sm[t - off] : 0;
    __syncthreads();
    incl += other;
    sm[t] = incl;
    __syncthreads();
  }
  if (i < n) offsets[i] = incl - v;
  if (t == 255) bsum[blockIdx.x] = incl;
}

__global__ __launch_bounds__(256) void k_scan2(const int* __restrict__ bsum,
                                               int* __restrict__ ebase,
                                               int* __restrict__ offsets,
                                               int nb, int n) {
  __shared__ int sm[256];
  const int t = threadIdx.x;
  const int v = (t < nb) ? bsum[t] : 0;
  int incl = v;
  sm[t] = incl;
  __syncthreads();
#pragma unroll
  for (int off = 1; off < 256; off <<= 1) {
    const int other = (t >= off) ? sm[t - off] : 0;
    __syncthreads();
    incl += other;
    sm[t] = incl;
    __syncthreads();
  }
  if (t < nb) ebase[t] = incl - v;
  if (t == 255) offsets[n] = incl;
}

__global__ __launch_bounds__(256) void k_scan3(int* __restrict__ offsets,
                                               int* __restrict__ cursors,
                                               const int* __restrict__ ebase, int n) {
  const int i = blockIdx.x * 256 + threadIdx.x;
  if (i >= n) return;
  const int o = offsets[i] + ebase[blockIdx.x];
  offsets[i] = o;
  cursors[i] = o;
}

__global__ __launch_bounds__(256) void k_bucket(const int* __restrict__ ei,
                                                int* __restrict__ cursors,
                                                int* __restrict__ esrc, int nE) {
  const int e = blockIdx.x * 256 + threadIdx.x;
  if (e >= nE) return;
  const int s = ei[e];
  const int d = ei[nE + e];
  const int pos = atomicAdd(&cursors[d], 1);
  esrc[pos] = s;
}

// ---------------- f32 -> bf16 for h, W1, W2 in one launch ----------------
__global__ __launch_bounds__(256) void k_tobf3(const float* __restrict__ h,
                                               const float* __restrict__ w1,
                                               const float* __restrict__ w2,
                                               uint2* __restrict__ hb,
                                               uint2* __restrict__ w1b,
                                               uint2* __restrict__ w2b,
                                               int nh4, int nw4) {
  const int total = nh4 + 2 * nw4;
  const int stride = gridDim.x * 256;
  for (int i = blockIdx.x * 256 + threadIdx.x; i < total; i += stride) {
    const float* src;
    uint2* dst;
    int off;
    if (i < nh4) { src = h; dst = hb; off = i; }
    else if (i < nh4 + nw4) { src = w1; dst = w1b; off = i - nh4; }
    else { src = w2; dst = w2b; off = i - nh4 - nw4; }
    const float4 v = reinterpret_cast<const float4*>(src)[off];
    uint2 p;
    p.x = (unsigned)f2bf(v.x) | ((unsigned)f2bf(v.y) << 16);
    p.y = (unsigned)f2bf(v.z) | ((unsigned)f2bf(v.w) << 16);
    dst[off] = p;
  }
}

// ---------------- gather (full-TLP): z[n] = (1+eps)*h[n] + sum h[esrc[e]] ----------------
// 32 lanes/node, 4 cols/lane (uint2 = 4 bf16), f32 accumulation. 1.6M threads.
__global__ __launch_bounds__(256) void k_gather(const unsigned short* __restrict__ hbf,
                                                const int* __restrict__ offsets,
                                                const int* __restrict__ esrc,
                                                const float* __restrict__ eps,
                                                unsigned short* __restrict__ zbf, int nNodes) {
  const int gid = blockIdx.x * 256 + threadIdx.x;
  const int node = gid >> 5;
  if (node >= nNodes) return;
  const int col4 = (threadIdx.x & 31) * 4;
  const float c = 1.0f + eps[0];

  const uint2 hv = *reinterpret_cast<const uint2*>(hbf + (size_t)node * HID + col4);
  float a0 = c * bflo(hv.x), a1 = c * bfhi(hv.x);
  float a2 = c * bflo(hv.y), a3 = c * bfhi(hv.y);

  const int beg = offsets[node], end = offsets[node + 1];
  int e = beg;
  for (; e + 1 < end; e += 2) {
    const int s0 = esrc[e], s1 = esrc[e + 1];
    const uint2 v0 = *reinterpret_cast<const uint2*>(hbf + (size_t)s0 * HID + col4);
    const uint2 v1 = *reinterpret_cast<const uint2*>(hbf + (size_t)s1 * HID + col4);
    a0 += bflo(v0.x) + bflo(v1.x);
    a1 += bfhi(v0.x) + bfhi(v1.x);
    a2 += bflo(v0.y) + bflo(v1.y);
    a3 += bfhi(v0.y) + bfhi(v1.y);
  }
  if (e < end) {
    const uint2 v0 = *reinterpret_cast<const uint2*>(hbf + (size_t)esrc[e] * HID + col4);
    a0 += bflo(v0.x); a1 += bfhi(v0.x); a2 += bflo(v0.y); a3 += bfhi(v0.y);
  }
  uint2 o;
  o.x = (unsigned)f2bf(a0) | ((unsigned)f2bf(a1) << 16);
  o.y = (unsigned)f2bf(a2) | ((unsigned)f2bf(a3) << 16);
  *reinterpret_cast<uint2*>(zbf + (size_t)node * HID + col4) = o;
}

// ---------------- fused MFMA: y1=relu(z@W1^T+b1); out=relu(LN(y1@W2^T+b2+h)) ----------------
// Per-wave 16-row tile, NO barriers (waves independent). y1 staged via wave-private LDS
// (C-layout -> A-fragment transpose). A-frags from global zbf; W1/W2 L1-hot.
__global__ __launch_bounds__(256) void k_mmf(const unsigned short* __restrict__ zbf,
                                             const unsigned short* __restrict__ w1,
                                             const unsigned short* __restrict__ w2,
                                             const float* __restrict__ b1,
                                             const float* __restrict__ b2,
                                             const float* __restrict__ h,
                                             const float* __restrict__ gamma,
                                             const float* __restrict__ beta,
                                             float* __restrict__ out, int nTiles) {
  __shared__ unsigned short yt[4][16][LDSW];
  const int wave = threadIdx.x >> 6;
  const int l = threadIdx.x & 63;
  const int mtile = blockIdx.x * 4 + wave;
  if (mtile >= nTiles) return;
  const int row0 = mtile * 16;
  const int lr = l & 15;
  const int lq = l >> 4;

  bf16x8 a[4];
#pragma unroll
  for (int ks = 0; ks < 4; ++ks)
    a[ks] = *reinterpret_cast<const bf16x8*>(zbf + (size_t)(row0 + lr) * HID + ks * 32 + lq * 8);

  f32x4 acc[8];
#pragma unroll
  for (int nt = 0; nt < 8; ++nt) acc[nt] = (f32x4){0.f, 0.f, 0.f, 0.f};
#pragma unroll
  for (int nt = 0; nt < 8; ++nt) {
    const unsigned short* wb = w1 + (size_t)(nt * 16 + lr) * HID + lq * 8;
#pragma unroll
    for (int ks = 0; ks < 4; ++ks) {
      const bf16x8 b = *reinterpret_cast<const bf16x8*>(wb + ks * 32);
      acc[nt] = __builtin_amdgcn_mfma_f32_16x16x32_bf16(a[ks], b, acc[nt], 0, 0, 0);
    }
  }

  // y1 = relu(acc + b1) -> wave-private LDS (C-layout: col=nt*16+lr, row-in-tile=lq*4+r)
#pragma unroll
  for (int nt = 0; nt < 8; ++nt) {
    const int cc = nt * 16 + lr;
    const float bs = b1[cc];
#pragma unroll
    for (int r = 0; r < 4; ++r)
      yt[wave][lq * 4 + r][cc] = f2bf(fmaxf(acc[nt][r] + bs, 0.f));
  }

  bf16x8 a2[4];
#pragma unroll
  for (int ks = 0; ks < 4; ++ks)
    a2[ks] = *reinterpret_cast<const bf16x8*>(&yt[wave][lr][ks * 32 + lq * 8]);

#pragma unroll
  for (int nt = 0; nt < 8; ++nt) acc[nt] = (f32x4){0.f, 0.f, 0.f, 0.f};
#pragma unroll
  for (int nt = 0; nt < 8; ++nt) {
    const unsigned short* wb = w2 + (size_t)(nt * 16 + lr) * HID + lq * 8;
#pragma unroll
    for (int ks = 0; ks < 4; ++ks) {
      const bf16x8 b = *reinterpret_cast<const bf16x8*>(wb + ks * 32);
      acc[nt] = __builtin_amdgcn_mfma_f32_16x16x32_bf16(a2[ks], b, acc[nt], 0, 0, 0);
    }
  }

  // bias + residual (f32 h)
#pragma unroll
  for (int nt = 0; nt < 8; ++nt) {
    const int cc = nt * 16 + lr;
    const float bs = b2[cc];
#pragma unroll
    for (int r = 0; r < 4; ++r) {
      const int row = row0 + lq * 4 + r;
      acc[nt][r] += bs + h[(size_t)row * HID + cc];
    }
  }

  // LayerNorm per row (row spans the 16-lane group) + relu + store
  float mu_[4], rstd_[4];
#pragma unroll
  for (int r = 0; r < 4; ++r) {
    float s = 0.f, ss = 0.f;
#pragma unroll
    for (int nt = 0; nt < 8; ++nt) { const float v = acc[nt][r]; s += v; ss += v * v; }
#pragma unroll
    for (int m = 1; m < 16; m <<= 1) {
      s += __shfl_xor(s, m, 64);
      ss += __shfl_xor(ss, m, 64);
    }
    const float mu = s * (1.f / 128.f);
    const float var = ss * (1.f / 128.f) - mu * mu;
    mu_[r] = mu;
    rstd_[r] = rsqrtf(var + LN_EPS);
  }
#pragma unroll
  for (int nt = 0; nt < 8; ++nt) {
    const int cc = nt * 16 + lr;
    const float g = gamma[cc], be = beta[cc];
#pragma unroll
    for (int r = 0; r < 4; ++r) {
      const int row = row0 + lq * 4 + r;
      const float o = (acc[nt][r] - mu_[r]) * rstd_[r] * g + be;
      out[(size_t)row * HID + cc] = fmaxf(o, 0.f);
    }
  }
}

extern "C" void kernel_launch(void* const* d_in, const int* in_sizes, int n_in,
                              void* d_out, int out_size, void* d_ws, size_t ws_size,
                              hipStream_t stream) {
  const float* h     = (const float*)d_in[0];
  const int*   ei    = (const int*)d_in[1];
  const float* W1    = (const float*)d_in[2];
  const float* b1    = (const float*)d_in[3];
  const float* W2    = (const float*)d_in[4];
  const float* b2    = (const float*)d_in[5];
  const float* eps   = (const float*)d_in[6];
  const float* gamma = (const float*)d_in[7];
  const float* beta  = (const float*)d_in[8];

  const int nNodes = in_sizes[0] / HID;     // 50000
  const int nE     = in_sizes[1] / 2;       // 640000
  const int nb     = (nNodes + 255) / 256;  // 196

  // ws layout (ints first, then 16B-aligned bf16 regions):
  int* counts  = (int*)d_ws;
  int* offsets = counts + nNodes;                 // @ 50000
  int* cursors = offsets + nNodes + 1;            // @ 100001
  int* bsum    = cursors + nNodes;                // @ 150001
  int* ebase   = bsum + nb;                       // @ 150197
  int* esrc    = counts + 150400;                 // @ 150400 (byte 601600, 16B-aligned)
  unsigned short* hbf  = (unsigned short*)(esrc + nE);   // 16B-aligned
  unsigned short* zbf  = hbf + (size_t)nNodes * HID;     // +12.8 MB
  unsigned short* w1bf = zbf + (size_t)nNodes * HID;     // +12.8 MB
  unsigned short* w2bf = w1bf + HID * HID;               // +32 KB (total ~28.8 MB)

  hipMemsetAsync(counts, 0, (size_t)nNodes * sizeof(int), stream);

  const int eblocks = (nE + 255) / 256;
  k_tobf3<<<2048, 256, 0, stream>>>(h, W1, W2, (uint2*)hbf, (uint2*)w1bf, (uint2*)w2bf,
                                    nNodes * HID / 4, HID * HID / 4);
  k_count<<<eblocks, 256, 0, stream>>>(ei, counts, nE);
  k_scan1<<<nb, 256, 0, stream>>>(counts, offsets, bsum, nNodes);
  k_scan2<<<1, 256, 0, stream>>>(bsum, ebase, offsets, nb, nNodes);
  k_scan3<<<nb, 256, 0, stream>>>(offsets, cursors, ebase, nNodes);
  k_bucket<<<eblocks, 256, 0, stream>>>(ei, cursors, esrc, nE);

  k_gather<<<(nNodes * 32 + 255) / 256, 256, 0, stream>>>(hbf, offsets, esrc, eps, zbf, nNodes);

  const int nTiles = nNodes / 16;            // 3125
  const int mblocks = (nTiles + 3) / 4;      // 782
  k_mmf<<<mblocks, 256, 0, stream>>>(zbf, w1bf, w2bf, b1, b2, h, gamma, beta,
                                     (float*)d_out, nTiles);
}

// Round 9
// 243.179 us; speedup vs baseline: 1.0638x; 1.0190x over previous
//
#include <hip/hip_runtime.h>

#define HID 128
#define LN_EPS 1e-5f
#define LDSW 136  // LDS row stride in shorts (272 B): b128 reads land at worst 2-way aliasing (free, m136)

typedef __attribute__((ext_vector_type(8))) short bf16x8;
typedef __attribute__((ext_vector_type(4))) float f32x4;

static __device__ __forceinline__ unsigned short f2bf(float f) {
  unsigned int x = __float_as_uint(f);
  x += 0x7fffu + ((x >> 16) & 1u);  // RNE
  return (unsigned short)(x >> 16);
}
static __device__ __forceinline__ float bflo(unsigned int u) { return __uint_as_float(u << 16); }
static __device__ __forceinline__ float bfhi(unsigned int u) { return __uint_as_float(u & 0xffff0000u); }

// ---------------- CSR build (counting sort by dst) ----------------
__global__ __launch_bounds__(256) void k_count(const int* __restrict__ ei,
                                               int* __restrict__ counts, int nE) {
  const int e = blockIdx.x * 256 + threadIdx.x;
  if (e >= nE) return;
  atomicAdd(&counts[ei[nE + e]], 1);
}

__global__ __launch_bounds__(256) void k_scan1(const int* __restrict__ counts,
                                               int* __restrict__ offsets,
                                               int* __restrict__ bsum, int n) {
  __shared__ int sm[256];
  const int t = threadIdx.x;
  const int i = blockIdx.x * 256 + t;
  const int v = (i < n) ? counts[i] : 0;
  int incl = v;
  sm[t] = incl;
  __syncthreads();
#pragma unroll
  for (int off = 1; off < 256; off <<= 1) {
    const int other = (t >= off) ? sm[t - off] : 0;
    __syncthreads();
    incl += other;
    sm[t] = incl;
    __syncthreads();
  }
  if (i < n) offsets[i] = incl - v;
  if (t == 255) bsum[blockIdx.x] = incl;
}

__global__ __launch_bounds__(256) void k_scan2(const int* __restrict__ bsum,
                                               int* __restrict__ ebase,
                                               int* __restrict__ offsets,
                                               int nb, int n) {
  __shared__ int sm[256];
  const int t = threadIdx.x;
  const int v = (t < nb) ? bsum[t] : 0;
  int incl = v;
  sm[t] = incl;
  __syncthreads();
#pragma unroll
  for (int off = 1; off < 256; off <<= 1) {
    const int other = (t >= off) ? sm[t - off] : 0;
    __syncthreads();
    incl += other;
    sm[t] = incl;
    __syncthreads();
  }
  if (t < nb) ebase[t] = incl - v;
  if (t == 255) offsets[n] = incl;
}

__global__ __launch_bounds__(256) void k_scan3(int* __restrict__ offsets,
                                               int* __restrict__ cursors,
                                               const int* __restrict__ ebase, int n) {
  const int i = blockIdx.x * 256 + threadIdx.x;
  if (i >= n) return;
  const int o = offsets[i] + ebase[blockIdx.x];
  offsets[i] = o;
  cursors[i] = o;
}

__global__ __launch_bounds__(256) void k_bucket(const int* __restrict__ ei,
                                                int* __restrict__ cursors,
                                                int* __restrict__ esrc, int nE) {
  const int e = blockIdx.x * 256 + threadIdx.x;
  if (e >= nE) return;
  const int s = ei[e];
  const int d = ei[nE + e];
  const int pos = atomicAdd(&cursors[d], 1);
  esrc[pos] = s;
}

// ---------------- f32 -> bf16 for h, W1, W2 in one launch ----------------
__global__ __launch_bounds__(256) void k_tobf3(const float* __restrict__ h,
                                               const float* __restrict__ w1,
                                               const float* __restrict__ w2,
                                               uint2* __restrict__ hb,
                                               uint2* __restrict__ w1b,
                                               uint2* __restrict__ w2b,
                                               int nh4, int nw4) {
  const int total = nh4 + 2 * nw4;
  const int stride = gridDim.x * 256;
  for (int i = blockIdx.x * 256 + threadIdx.x; i < total; i += stride) {
    const float* src;
    uint2* dst;
    int off;
    if (i < nh4) { src = h; dst = hb; off = i; }
    else if (i < nh4 + nw4) { src = w1; dst = w1b; off = i - nh4; }
    else { src = w2; dst = w2b; off = i - nh4 - nw4; }
    const float4 v = reinterpret_cast<const float4*>(src)[off];
    uint2 p;
    p.x = (unsigned)f2bf(v.x) | ((unsigned)f2bf(v.y) << 16);
    p.y = (unsigned)f2bf(v.z) | ((unsigned)f2bf(v.w) << 16);
    dst[off] = p;
  }
}

// ---------------- gather (full-TLP): z[n] = (1+eps)*h[n] + sum h[esrc[e]] ----------------
__global__ __launch_bounds__(256) void k_gather(const unsigned short* __restrict__ hbf,
                                                const int* __restrict__ offsets,
                                                const int* __restrict__ esrc,
                                                const float* __restrict__ eps,
                                                unsigned short* __restrict__ zbf, int nNodes) {
  const int gid = blockIdx.x * 256 + threadIdx.x;
  const int node = gid >> 5;
  if (node >= nNodes) return;
  const int col4 = (threadIdx.x & 31) * 4;
  const float c = 1.0f + eps[0];

  const uint2 hv = *reinterpret_cast<const uint2*>(hbf + (size_t)node * HID + col4);
  float a0 = c * bflo(hv.x), a1 = c * bfhi(hv.x);
  float a2 = c * bflo(hv.y), a3 = c * bfhi(hv.y);

  const int beg = offsets[node], end = offsets[node + 1];
  int e = beg;
  for (; e + 1 < end; e += 2) {
    const int s0 = esrc[e], s1 = esrc[e + 1];
    const uint2 v0 = *reinterpret_cast<const uint2*>(hbf + (size_t)s0 * HID + col4);
    const uint2 v1 = *reinterpret_cast<const uint2*>(hbf + (size_t)s1 * HID + col4);
    a0 += bflo(v0.x) + bflo(v1.x);
    a1 += bfhi(v0.x) + bfhi(v1.x);
    a2 += bflo(v0.y) + bflo(v1.y);
    a3 += bfhi(v0.y) + bfhi(v1.y);
  }
  if (e < end) {
    const uint2 v0 = *reinterpret_cast<const uint2*>(hbf + (size_t)esrc[e] * HID + col4);
    a0 += bflo(v0.x); a1 += bfhi(v0.x); a2 += bflo(v0.y); a3 += bfhi(v0.y);
  }
  uint2 o;
  o.x = (unsigned)f2bf(a0) | ((unsigned)f2bf(a1) << 16);
  o.y = (unsigned)f2bf(a2) | ((unsigned)f2bf(a3) << 16);
  *reinterpret_cast<uint2*>(zbf + (size_t)node * HID + col4) = o;
}

// ---------------- fused MFMA, column-split: 1 block = 1 16-row tile, 4 waves ----------------
// Wave w computes column-tiles nt = {2w, 2w+1} for BOTH GEMMs (2 MFMA accs).
// y1 shared in LDS [16][LDSW]; LN row-stats combined via tiny LDS exchange.
// Per-wave VMEM ~36 instrs; grid = 3125 blocks -> ~32 resident waves/CU.
__global__ __launch_bounds__(256) void k_mmf(const unsigned short* __restrict__ zbf,
                                             const unsigned short* __restrict__ w1,
                                             const unsigned short* __restrict__ w2,
                                             const float* __restrict__ b1,
                                             const float* __restrict__ b2,
                                             const float* __restrict__ h,
                                             const float* __restrict__ gamma,
                                             const float* __restrict__ beta,
                                             float* __restrict__ out, int nTiles) {
  __shared__ unsigned short yt[16][LDSW];   // 4.25 KB
  __shared__ float lnp[16][4][2];           // per-row per-wave (sum, sumsq)
  const int wave = threadIdx.x >> 6;        // 0..3
  const int l = threadIdx.x & 63;
  const int mtile = blockIdx.x;
  if (mtile >= nTiles) return;              // uniform per block
  const int row0 = mtile * 16;
  const int lr = l & 15;
  const int lq = l >> 4;

  // A-frags from zbf (all 4 waves load the same lines; L1 broadcasts)
  bf16x8 a[4];
#pragma unroll
  for (int ks = 0; ks < 4; ++ks)
    a[ks] = *reinterpret_cast<const bf16x8*>(zbf + (size_t)(row0 + lr) * HID + ks * 32 + lq * 8);

  // GEMM1: this wave's 2 column-tiles
  f32x4 acc[2];
#pragma unroll
  for (int j = 0; j < 2; ++j) acc[j] = (f32x4){0.f, 0.f, 0.f, 0.f};
#pragma unroll
  for (int j = 0; j < 2; ++j) {
    const int nt = wave * 2 + j;
    const unsigned short* wb = w1 + (size_t)(nt * 16 + lr) * HID + lq * 8;
#pragma unroll
    for (int ks = 0; ks < 4; ++ks) {
      const bf16x8 b = *reinterpret_cast<const bf16x8*>(wb + ks * 32);
      acc[j] = __builtin_amdgcn_mfma_f32_16x16x32_bf16(a[ks], b, acc[j], 0, 0, 0);
    }
  }

  // y1 = relu(acc + b1) -> shared LDS (C-layout: col=nt*16+lr, row=lq*4+r)
#pragma unroll
  for (int j = 0; j < 2; ++j) {
    const int cc = (wave * 2 + j) * 16 + lr;
    const float bs = b1[cc];
#pragma unroll
    for (int r = 0; r < 4; ++r)
      yt[lq * 4 + r][cc] = f2bf(fmaxf(acc[j][r] + bs, 0.f));
  }
  __syncthreads();

  // GEMM2: full y1 rows as A2-frags
  bf16x8 a2[4];
#pragma unroll
  for (int ks = 0; ks < 4; ++ks)
    a2[ks] = *reinterpret_cast<const bf16x8*>(&yt[lr][ks * 32 + lq * 8]);

#pragma unroll
  for (int j = 0; j < 2; ++j) acc[j] = (f32x4){0.f, 0.f, 0.f, 0.f};
#pragma unroll
  for (int j = 0; j < 2; ++j) {
    const int nt = wave * 2 + j;
    const unsigned short* wb = w2 + (size_t)(nt * 16 + lr) * HID + lq * 8;
#pragma unroll
    for (int ks = 0; ks < 4; ++ks) {
      const bf16x8 b = *reinterpret_cast<const bf16x8*>(wb + ks * 32);
      acc[j] = __builtin_amdgcn_mfma_f32_16x16x32_bf16(a2[ks], b, acc[j], 0, 0, 0);
    }
  }

  // bias + residual (f32 h)
#pragma unroll
  for (int j = 0; j < 2; ++j) {
    const int cc = (wave * 2 + j) * 16 + lr;
    const float bs = b2[cc];
#pragma unroll
    for (int r = 0; r < 4; ++r) {
      const int row = row0 + lq * 4 + r;
      acc[j][r] += bs + h[(size_t)row * HID + cc];
    }
  }

  // per-wave partial LN stats (sum over 2 nt x 16 lanes), lane lr==0 publishes
#pragma unroll
  for (int r = 0; r < 4; ++r) {
    float s = acc[0][r] + acc[1][r];
    float ss = acc[0][r] * acc[0][r] + acc[1][r] * acc[1][r];
#pragma unroll
    for (int m = 1; m < 16; m <<= 1) {
      s += __shfl_xor(s, m, 64);
      ss += __shfl_xor(ss, m, 64);
    }
    if (lr == 0) {
      lnp[lq * 4 + r][wave][0] = s;
      lnp[lq * 4 + r][wave][1] = ss;
    }
  }
  __syncthreads();

  // combine 4 waves' partials (broadcast LDS reads), finish LN + relu + store
  float mu_[4], rstd_[4];
#pragma unroll
  for (int r = 0; r < 4; ++r) {
    const int rt = lq * 4 + r;
    float s = 0.f, ss = 0.f;
#pragma unroll
    for (int w = 0; w < 4; ++w) {
      const float2 p = *reinterpret_cast<const float2*>(&lnp[rt][w][0]);
      s += p.x;
      ss += p.y;
    }
    const float mu = s * (1.f / 128.f);
    const float var = ss * (1.f / 128.f) - mu * mu;
    mu_[r] = mu;
    rstd_[r] = rsqrtf(var + LN_EPS);
  }
#pragma unroll
  for (int j = 0; j < 2; ++j) {
    const int cc = (wave * 2 + j) * 16 + lr;
    const float g = gamma[cc], be = beta[cc];
#pragma unroll
    for (int r = 0; r < 4; ++r) {
      const int row = row0 + lq * 4 + r;
      const float o = (acc[j][r] - mu_[r]) * rstd_[r] * g + be;
      out[(size_t)row * HID + cc] = fmaxf(o, 0.f);
    }
  }
}

extern "C" void kernel_launch(void* const* d_in, const int* in_sizes, int n_in,
                              void* d_out, int out_size, void* d_ws, size_t ws_size,
                              hipStream_t stream) {
  const float* h     = (const float*)d_in[0];
  const int*   ei    = (const int*)d_in[1];
  const float* W1    = (const float*)d_in[2];
  const float* b1    = (const float*)d_in[3];
  const float* W2    = (const float*)d_in[4];
  const float* b2    = (const float*)d_in[5];
  const float* eps   = (const float*)d_in[6];
  const float* gamma = (const float*)d_in[7];
  const float* beta  = (const float*)d_in[8];

  const int nNodes = in_sizes[0] / HID;     // 50000
  const int nE     = in_sizes[1] / 2;       // 640000
  const int nb     = (nNodes + 255) / 256;  // 196

  // ws layout (ints first, then 16B-aligned bf16 regions):
  int* counts  = (int*)d_ws;
  int* offsets = counts + nNodes;                 // @ 50000
  int* cursors = offsets + nNodes + 1;            // @ 100001
  int* bsum    = cursors + nNodes;                // @ 150001
  int* ebase   = bsum + nb;                       // @ 150197
  int* esrc    = counts + 150400;                 // @ 150400 (byte 601600, 16B-aligned)
  unsigned short* hbf  = (unsigned short*)(esrc + nE);   // 16B-aligned
  unsigned short* zbf  = hbf + (size_t)nNodes * HID;     // +12.8 MB
  unsigned short* w1bf = zbf + (size_t)nNodes * HID;     // +12.8 MB
  unsigned short* w2bf = w1bf + HID * HID;               // +32 KB (total ~28.8 MB)

  hipMemsetAsync(counts, 0, (size_t)nNodes * sizeof(int), stream);

  const int eblocks = (nE + 255) / 256;
  k_tobf3<<<2048, 256, 0, stream>>>(h, W1, W2, (uint2*)hbf, (uint2*)w1bf, (uint2*)w2bf,
                                    nNodes * HID / 4, HID * HID / 4);
  k_count<<<eblocks, 256, 0, stream>>>(ei, counts, nE);
  k_scan1<<<nb, 256, 0, stream>>>(counts, offsets, bsum, nNodes);
  k_scan2<<<1, 256, 0, stream>>>(bsum, ebase, offsets, nb, nNodes);
  k_scan3<<<nb, 256, 0, stream>>>(offsets, cursors, ebase, nNodes);
  k_bucket<<<eblocks, 256, 0, stream>>>(ei, cursors, esrc, nE);

  k_gather<<<(nNodes * 32 + 255) / 256, 256, 0, stream>>>(hbf, offsets, esrc, eps, zbf, nNodes);

  const int nTiles = nNodes / 16;            // 3125
  k_mmf<<<nTiles, 256, 0, stream>>>(zbf, w1bf, w2bf, b1, b2, h, gamma, beta,
                                    (float*)d_out, nTiles);
}

// Round 10
// 212.727 us; speedup vs baseline: 1.2161x; 1.1432x over previous
//
#include <hip/hip_runtime.h>

#define HID 128
#define LN_EPS 1e-5f
#define LDSW 136  // LDS row stride in shorts (272 B): b128 reads at worst 2-way aliasing (free, m136)

typedef __attribute__((ext_vector_type(8))) short bf16x8;
typedef __attribute__((ext_vector_type(4))) float f32x4;

static __device__ __forceinline__ unsigned short f2bf(float f) {
  unsigned int x = __float_as_uint(f);
  x += 0x7fffu + ((x >> 16) & 1u);  // RNE
  return (unsigned short)(x >> 16);
}
static __device__ __forceinline__ float bflo(unsigned int u) { return __uint_as_float(u << 16); }
static __device__ __forceinline__ float bfhi(unsigned int u) { return __uint_as_float(u & 0xffff0000u); }

// ---- fused: bf16 converts (BW-bound blocks) + rank pass (atomic-bound blocks) ----
// rank[e] = atomicAdd(&counts[dst],1): ONE atomic pass yields counts AND slot ranks.
__global__ __launch_bounds__(256) void k_cvt_rank(const float* __restrict__ h,
                                                  const float* __restrict__ w1,
                                                  const float* __restrict__ w2,
                                                  uint2* __restrict__ hb,
                                                  uint2* __restrict__ w1b,
                                                  uint2* __restrict__ w2b,
                                                  int nh4, int nw4,
                                                  const int* __restrict__ ei,
                                                  int* __restrict__ counts,
                                                  int* __restrict__ rank,
                                                  int nE, int EB) {
  if ((int)blockIdx.x < EB) {
    const int e = blockIdx.x * 256 + threadIdx.x;
    if (e < nE) {
      const int d = ei[nE + e];
      rank[e] = atomicAdd(&counts[d], 1);  // coalesced rank store
    }
    return;
  }
  const int total = nh4 + 2 * nw4;
  const int stride = (gridDim.x - EB) * 256;
  for (int i = (blockIdx.x - EB) * 256 + threadIdx.x; i < total; i += stride) {
    const float* src;
    uint2* dst;
    int off;
    if (i < nh4) { src = h; dst = hb; off = i; }
    else if (i < nh4 + nw4) { src = w1; dst = w1b; off = i - nh4; }
    else { src = w2; dst = w2b; off = i - nh4 - nw4; }
    const float4 v = reinterpret_cast<const float4*>(src)[off];
    uint2 p;
    p.x = (unsigned)f2bf(v.x) | ((unsigned)f2bf(v.y) << 16);
    p.y = (unsigned)f2bf(v.z) | ((unsigned)f2bf(v.w) << 16);
    dst[off] = p;
  }
}

// ---------------- hierarchical scan of counts -> final offsets ----------------
__global__ __launch_bounds__(256) void k_scan1(const int* __restrict__ counts,
                                               int* __restrict__ offsets,
                                               int* __restrict__ bsum, int n) {
  __shared__ int sm[256];
  const int t = threadIdx.x;
  const int i = blockIdx.x * 256 + t;
  const int v = (i < n) ? counts[i] : 0;
  int incl = v;
  sm[t] = incl;
  __syncthreads();
#pragma unroll
  for (int off = 1; off < 256; off <<= 1) {
    const int other = (t >= off) ? sm[t - off] : 0;
    __syncthreads();
    incl += other;
    sm[t] = incl;
    __syncthreads();
  }
  if (i < n) offsets[i] = incl - v;
  if (t == 255) bsum[blockIdx.x] = incl;
}

__global__ __launch_bounds__(256) void k_scan2(const int* __restrict__ bsum,
                                               int* __restrict__ ebase,
                                               int* __restrict__ offsets,
                                               int nb, int n) {
  __shared__ int sm[256];
  const int t = threadIdx.x;
  const int v = (t < nb) ? bsum[t] : 0;
  int incl = v;
  sm[t] = incl;
  __syncthreads();
#pragma unroll
  for (int off = 1; off < 256; off <<= 1) {
    const int other = (t >= off) ? sm[t - off] : 0;
    __syncthreads();
    incl += other;
    sm[t] = incl;
    __syncthreads();
  }
  if (t < nb) ebase[t] = incl - v;
  if (t == 255) offsets[n] = incl;  // zero-padded -> grand total
}

__global__ __launch_bounds__(256) void k_scan3(int* __restrict__ offsets,
                                               const int* __restrict__ ebase, int n) {
  const int i = blockIdx.x * 256 + threadIdx.x;
  if (i >= n) return;
  offsets[i] += ebase[blockIdx.x];
}

// ---------------- atomic-free scatter: esrc[offsets[d] + rank[e]] = src ----------------
// Plain 4B stores write-allocate in local XCD L2 (esrc = 2.56 MB total); no RMW round-trip.
__global__ __launch_bounds__(256) void k_scat(const int* __restrict__ ei,
                                              const int* __restrict__ rank,
                                              const int* __restrict__ offsets,
                                              int* __restrict__ esrc, int nE) {
  const int e = blockIdx.x * 256 + threadIdx.x;
  if (e >= nE) return;
  const int d = ei[nE + e];
  esrc[offsets[d] + rank[e]] = ei[e];
}

// ---------------- gather (full-TLP): z[n] = (1+eps)*h[n] + sum h[esrc[e]] ----------------
__global__ __launch_bounds__(256) void k_gather(const unsigned short* __restrict__ hbf,
                                                const int* __restrict__ offsets,
                                                const int* __restrict__ esrc,
                                                const float* __restrict__ eps,
                                                unsigned short* __restrict__ zbf, int nNodes) {
  const int gid = blockIdx.x * 256 + threadIdx.x;
  const int node = gid >> 5;
  if (node >= nNodes) return;
  const int col4 = (threadIdx.x & 31) * 4;
  const float c = 1.0f + eps[0];

  const uint2 hv = *reinterpret_cast<const uint2*>(hbf + (size_t)node * HID + col4);
  float a0 = c * bflo(hv.x), a1 = c * bfhi(hv.x);
  float a2 = c * bflo(hv.y), a3 = c * bfhi(hv.y);

  const int beg = offsets[node], end = offsets[node + 1];
  int e = beg;
  for (; e + 1 < end; e += 2) {
    const int s0 = esrc[e], s1 = esrc[e + 1];
    const uint2 v0 = *reinterpret_cast<const uint2*>(hbf + (size_t)s0 * HID + col4);
    const uint2 v1 = *reinterpret_cast<const uint2*>(hbf + (size_t)s1 * HID + col4);
    a0 += bflo(v0.x) + bflo(v1.x);
    a1 += bfhi(v0.x) + bfhi(v1.x);
    a2 += bflo(v0.y) + bflo(v1.y);
    a3 += bfhi(v0.y) + bfhi(v1.y);
  }
  if (e < end) {
    const uint2 v0 = *reinterpret_cast<const uint2*>(hbf + (size_t)esrc[e] * HID + col4);
    a0 += bflo(v0.x); a1 += bfhi(v0.x); a2 += bflo(v0.y); a3 += bfhi(v0.y);
  }
  uint2 o;
  o.x = (unsigned)f2bf(a0) | ((unsigned)f2bf(a1) << 16);
  o.y = (unsigned)f2bf(a2) | ((unsigned)f2bf(a3) << 16);
  *reinterpret_cast<uint2*>(zbf + (size_t)node * HID + col4) = o;
}

// ---------------- fused MFMA, column-split (unchanged from R9) ----------------
__global__ __launch_bounds__(256) void k_mmf(const unsigned short* __restrict__ zbf,
                                             const unsigned short* __restrict__ w1,
                                             const unsigned short* __restrict__ w2,
                                             const float* __restrict__ b1,
                                             const float* __restrict__ b2,
                                             const float* __restrict__ h,
                                             const float* __restrict__ gamma,
                                             const float* __restrict__ beta,
                                             float* __restrict__ out, int nTiles) {
  __shared__ unsigned short yt[16][LDSW];
  __shared__ float lnp[16][4][2];
  const int wave = threadIdx.x >> 6;
  const int l = threadIdx.x & 63;
  const int mtile = blockIdx.x;
  if (mtile >= nTiles) return;
  const int row0 = mtile * 16;
  const int lr = l & 15;
  const int lq = l >> 4;

  bf16x8 a[4];
#pragma unroll
  for (int ks = 0; ks < 4; ++ks)
    a[ks] = *reinterpret_cast<const bf16x8*>(zbf + (size_t)(row0 + lr) * HID + ks * 32 + lq * 8);

  f32x4 acc[2];
#pragma unroll
  for (int j = 0; j < 2; ++j) acc[j] = (f32x4){0.f, 0.f, 0.f, 0.f};
#pragma unroll
  for (int j = 0; j < 2; ++j) {
    const int nt = wave * 2 + j;
    const unsigned short* wb = w1 + (size_t)(nt * 16 + lr) * HID + lq * 8;
#pragma unroll
    for (int ks = 0; ks < 4; ++ks) {
      const bf16x8 b = *reinterpret_cast<const bf16x8*>(wb + ks * 32);
      acc[j] = __builtin_amdgcn_mfma_f32_16x16x32_bf16(a[ks], b, acc[j], 0, 0, 0);
    }
  }

#pragma unroll
  for (int j = 0; j < 2; ++j) {
    const int cc = (wave * 2 + j) * 16 + lr;
    const float bs = b1[cc];
#pragma unroll
    for (int r = 0; r < 4; ++r)
      yt[lq * 4 + r][cc] = f2bf(fmaxf(acc[j][r] + bs, 0.f));
  }
  __syncthreads();

  bf16x8 a2[4];
#pragma unroll
  for (int ks = 0; ks < 4; ++ks)
    a2[ks] = *reinterpret_cast<const bf16x8*>(&yt[lr][ks * 32 + lq * 8]);

#pragma unroll
  for (int j = 0; j < 2; ++j) acc[j] = (f32x4){0.f, 0.f, 0.f, 0.f};
#pragma unroll
  for (int j = 0; j < 2; ++j) {
    const int nt = wave * 2 + j;
    const unsigned short* wb = w2 + (size_t)(nt * 16 + lr) * HID + lq * 8;
#pragma unroll
    for (int ks = 0; ks < 4; ++ks) {
      const bf16x8 b = *reinterpret_cast<const bf16x8*>(wb + ks * 32);
      acc[j] = __builtin_amdgcn_mfma_f32_16x16x32_bf16(a2[ks], b, acc[j], 0, 0, 0);
    }
  }

#pragma unroll
  for (int j = 0; j < 2; ++j) {
    const int cc = (wave * 2 + j) * 16 + lr;
    const float bs = b2[cc];
#pragma unroll
    for (int r = 0; r < 4; ++r) {
      const int row = row0 + lq * 4 + r;
      acc[j][r] += bs + h[(size_t)row * HID + cc];
    }
  }

#pragma unroll
  for (int r = 0; r < 4; ++r) {
    float s = acc[0][r] + acc[1][r];
    float ss = acc[0][r] * acc[0][r] + acc[1][r] * acc[1][r];
#pragma unroll
    for (int m = 1; m < 16; m <<= 1) {
      s += __shfl_xor(s, m, 64);
      ss += __shfl_xor(ss, m, 64);
    }
    if (lr == 0) {
      lnp[lq * 4 + r][wave][0] = s;
      lnp[lq * 4 + r][wave][1] = ss;
    }
  }
  __syncthreads();

  float mu_[4], rstd_[4];
#pragma unroll
  for (int r = 0; r < 4; ++r) {
    const int rt = lq * 4 + r;
    float s = 0.f, ss = 0.f;
#pragma unroll
    for (int w = 0; w < 4; ++w) {
      const float2 p = *reinterpret_cast<const float2*>(&lnp[rt][w][0]);
      s += p.x;
      ss += p.y;
    }
    const float mu = s * (1.f / 128.f);
    const float var = ss * (1.f / 128.f) - mu * mu;
    mu_[r] = mu;
    rstd_[r] = rsqrtf(var + LN_EPS);
  }
#pragma unroll
  for (int j = 0; j < 2; ++j) {
    const int cc = (wave * 2 + j) * 16 + lr;
    const float g = gamma[cc], be = beta[cc];
#pragma unroll
    for (int r = 0; r < 4; ++r) {
      const int row = row0 + lq * 4 + r;
      const float o = (acc[j][r] - mu_[r]) * rstd_[r] * g + be;
      out[(size_t)row * HID + cc] = fmaxf(o, 0.f);
    }
  }
}

extern "C" void kernel_launch(void* const* d_in, const int* in_sizes, int n_in,
                              void* d_out, int out_size, void* d_ws, size_t ws_size,
                              hipStream_t stream) {
  const float* h     = (const float*)d_in[0];
  const int*   ei    = (const int*)d_in[1];
  const float* W1    = (const float*)d_in[2];
  const float* b1    = (const float*)d_in[3];
  const float* W2    = (const float*)d_in[4];
  const float* b2    = (const float*)d_in[5];
  const float* eps   = (const float*)d_in[6];
  const float* gamma = (const float*)d_in[7];
  const float* beta  = (const float*)d_in[8];

  const int nNodes = in_sizes[0] / HID;     // 50000
  const int nE     = in_sizes[1] / 2;       // 640000
  const int nb     = (nNodes + 255) / 256;  // 196
  const int nh4    = nNodes * HID / 4;      // 1.6M
  const int nw4    = HID * HID / 4;         // 4096

  // ws layout (ints, bf16 regions 16B-aligned):
  // counts[50000] | offsets[50001] | bsum[196] | ebase[196] | pad | rank[640000] | esrc[640000] | hbf | zbf | w1bf | w2bf
  int* counts  = (int*)d_ws;
  int* offsets = counts + nNodes;                 // @ 50000
  int* bsum    = offsets + nNodes + 1;            // @ 100001
  int* ebase   = bsum + nb;                       // @ 100197
  int* rank    = counts + 100800;                 // @ 100800 (byte 403200, 16B-aligned)
  int* esrc    = rank + nE;                       // @ 740800
  unsigned short* hbf  = (unsigned short*)(esrc + nE);   // byte 5,523,200 (16B-aligned)
  unsigned short* zbf  = hbf + (size_t)nNodes * HID;     // +12.8 MB
  unsigned short* w1bf = zbf + (size_t)nNodes * HID;     // +12.8 MB
  unsigned short* w2bf = w1bf + HID * HID;               // +32 KB (total ~31.2 MB)

  hipMemsetAsync(counts, 0, (size_t)nNodes * sizeof(int), stream);

  const int EB = (nE + 255) / 256;          // 2500 edge blocks
  k_cvt_rank<<<EB + 2048, 256, 0, stream>>>(h, W1, W2, (uint2*)hbf, (uint2*)w1bf, (uint2*)w2bf,
                                            nh4, nw4, ei, counts, rank, nE, EB);
  k_scan1<<<nb, 256, 0, stream>>>(counts, offsets, bsum, nNodes);
  k_scan2<<<1, 256, 0, stream>>>(bsum, ebase, offsets, nb, nNodes);
  k_scan3<<<nb, 256, 0, stream>>>(offsets, ebase, nNodes);
  k_scat<<<EB, 256, 0, stream>>>(ei, rank, offsets, esrc, nE);

  k_gather<<<(nNodes * 32 + 255) / 256, 256, 0, stream>>>(hbf, offsets, esrc, eps, zbf, nNodes);

  const int nTiles = nNodes / 16;            // 3125
  k_mmf<<<nTiles, 256, 0, stream>>>(zbf, w1bf, w2bf, b1, b2, h, gamma, beta,
                                    (float*)d_out, nTiles);
}

// Round 11
// 203.142 us; speedup vs baseline: 1.2735x; 1.0472x over previous
//
#include <hip/hip_runtime.h>

#define HID 128
#define LN_EPS 1e-5f
#define LDSW 136  // LDS row stride in shorts (272 B): b128 reads at worst 2-way aliasing (free, m136)

typedef __attribute__((ext_vector_type(8))) short bf16x8;
typedef __attribute__((ext_vector_type(4))) float f32x4;

static __device__ __forceinline__ unsigned short f2bf(float f) {
  unsigned int x = __float_as_uint(f);
  x += 0x7fffu + ((x >> 16) & 1u);  // RNE
  return (unsigned short)(x >> 16);
}
static __device__ __forceinline__ float bflo(unsigned int u) { return __uint_as_float(u << 16); }
static __device__ __forceinline__ float bfhi(unsigned int u) { return __uint_as_float(u & 0xffff0000u); }

// ---- fused: bf16 converts (BW-bound blocks) + rank pass (atomic-bound blocks) ----
__global__ __launch_bounds__(256) void k_cvt_rank(const float* __restrict__ h,
                                                  const float* __restrict__ w1,
                                                  const float* __restrict__ w2,
                                                  uint2* __restrict__ hb,
                                                  uint2* __restrict__ w1b,
                                                  uint2* __restrict__ w2b,
                                                  int nh4, int nw4,
                                                  const int* __restrict__ ei,
                                                  int* __restrict__ counts,
                                                  int* __restrict__ rank,
                                                  int nE, int EB) {
  if ((int)blockIdx.x < EB) {
    const int e = blockIdx.x * 256 + threadIdx.x;
    if (e < nE) {
      const int d = ei[nE + e];
      rank[e] = atomicAdd(&counts[d], 1);  // one atomic pass: counts AND slot ranks
    }
    return;
  }
  const int total = nh4 + 2 * nw4;
  const int stride = (gridDim.x - EB) * 256;
  for (int i = (blockIdx.x - EB) * 256 + threadIdx.x; i < total; i += stride) {
    const float* src;
    uint2* dst;
    int off;
    if (i < nh4) { src = h; dst = hb; off = i; }
    else if (i < nh4 + nw4) { src = w1; dst = w1b; off = i - nh4; }
    else { src = w2; dst = w2b; off = i - nh4 - nw4; }
    const float4 v = reinterpret_cast<const float4*>(src)[off];
    uint2 p;
    p.x = (unsigned)f2bf(v.x) | ((unsigned)f2bf(v.y) << 16);
    p.y = (unsigned)f2bf(v.z) | ((unsigned)f2bf(v.w) << 16);
    dst[off] = p;
  }
}

// ---- single-pass scan, decoupled lookback. 196 blocks (< 256 CUs: all co-resident).
// st[b] packs (flag<<32)|inclusive_value; flag 1=partial, 2=prefix. Zeroed by memset.
// Publish via atomicExch, poll via atomicAdd(p,0) - device-scope, safe across XCDs.
__global__ __launch_bounds__(256) void k_scanLB(const int* __restrict__ counts,
                                                int* __restrict__ offsets,
                                                unsigned long long* st, int n, int nb) {
  __shared__ int sm[256];
  __shared__ float baseSh_f;  // reuse as raw bits container for int base
  __shared__ int baseSh;
  const int t = threadIdx.x;
  const int bid = blockIdx.x;
  const int i = bid * 256 + t;
  const int v = (i < n) ? counts[i] : 0;
  int incl = v;
  sm[t] = incl;
  __syncthreads();
#pragma unroll
  for (int off = 1; off < 256; off <<= 1) {
    const int other = (t >= off) ? sm[t - off] : 0;
    __syncthreads();
    incl += other;
    sm[t] = incl;
    __syncthreads();
  }
  const int total = sm[255];

  if (bid == 0) {
    if (t == 0) {
      atomicExch(&st[0], (2ULL << 32) | (unsigned)total);
      baseSh = 0;
    }
  } else {
    if (t == 255)  // publish partial promptly (different wave than the lookback spinner)
      atomicExch(&st[bid], (1ULL << 32) | (unsigned)total);
    if (t == 0) {  // lookback
      long long base = 0;
      int j = bid - 1;
      while (j >= 0) {
        unsigned long long p;
        while (((p = atomicAdd(&st[j], 0ULL)) >> 32) == 0) __builtin_amdgcn_s_sleep(1);
        base += (unsigned)p;
        if ((p >> 32) == 2ULL) break;
        --j;
      }
      atomicExch(&st[bid], (2ULL << 32) | (unsigned)(base + total));
      baseSh = (int)base;
    }
  }
  __syncthreads();
  const int base = baseSh;
  if (i < n) offsets[i] = base + incl - v;
  if (bid == nb - 1 && t == 255) offsets[n] = base + total;
  (void)baseSh_f;
}

// ---- atomic-free scatter: esrc[offsets[d] + rank[e]] = src ----
__global__ __launch_bounds__(256) void k_scat(const int* __restrict__ ei,
                                              const int* __restrict__ rank,
                                              const int* __restrict__ offsets,
                                              int* __restrict__ esrc, int nE) {
  const int e = blockIdx.x * 256 + threadIdx.x;
  if (e >= nE) return;
  const int d = ei[nE + e];
  esrc[offsets[d] + rank[e]] = ei[e];
}

// ---- gather (full-TLP, 4-deep MLP): z[n] = (1+eps)*h[n] + sum h[esrc[e]] ----
__global__ __launch_bounds__(256) void k_gather(const unsigned short* __restrict__ hbf,
                                                const int* __restrict__ offsets,
                                                const int* __restrict__ esrc,
                                                const float* __restrict__ eps,
                                                unsigned short* __restrict__ zbf, int nNodes) {
  const int gid = blockIdx.x * 256 + threadIdx.x;
  const int node = gid >> 5;
  if (node >= nNodes) return;
  const int col4 = (threadIdx.x & 31) * 4;
  const float c = 1.0f + eps[0];

  const uint2 hv = *reinterpret_cast<const uint2*>(hbf + (size_t)node * HID + col4);
  float a0 = c * bflo(hv.x), a1 = c * bfhi(hv.x);
  float a2 = c * bflo(hv.y), a3 = c * bfhi(hv.y);

  const int beg = offsets[node], end = offsets[node + 1];
  int e = beg;
  for (; e + 3 < end; e += 4) {  // 4 independent row loads in flight
    const int s0 = esrc[e], s1 = esrc[e + 1], s2 = esrc[e + 2], s3 = esrc[e + 3];
    const uint2 v0 = *reinterpret_cast<const uint2*>(hbf + (size_t)s0 * HID + col4);
    const uint2 v1 = *reinterpret_cast<const uint2*>(hbf + (size_t)s1 * HID + col4);
    const uint2 v2 = *reinterpret_cast<const uint2*>(hbf + (size_t)s2 * HID + col4);
    const uint2 v3 = *reinterpret_cast<const uint2*>(hbf + (size_t)s3 * HID + col4);
    a0 += (bflo(v0.x) + bflo(v1.x)) + (bflo(v2.x) + bflo(v3.x));
    a1 += (bfhi(v0.x) + bfhi(v1.x)) + (bfhi(v2.x) + bfhi(v3.x));
    a2 += (bflo(v0.y) + bflo(v1.y)) + (bflo(v2.y) + bflo(v3.y));
    a3 += (bfhi(v0.y) + bfhi(v1.y)) + (bfhi(v2.y) + bfhi(v3.y));
  }
  for (; e < end; ++e) {
    const uint2 v0 = *reinterpret_cast<const uint2*>(hbf + (size_t)esrc[e] * HID + col4);
    a0 += bflo(v0.x); a1 += bfhi(v0.x); a2 += bflo(v0.y); a3 += bfhi(v0.y);
  }
  uint2 o;
  o.x = (unsigned)f2bf(a0) | ((unsigned)f2bf(a1) << 16);
  o.y = (unsigned)f2bf(a2) | ((unsigned)f2bf(a3) << 16);
  *reinterpret_cast<uint2*>(zbf + (size_t)node * HID + col4) = o;
}

// ---- fused MFMA, column-split; h-residual prefetched at top (T14 issue-early) ----
__global__ __launch_bounds__(256) void k_mmf(const unsigned short* __restrict__ zbf,
                                             const unsigned short* __restrict__ w1,
                                             const unsigned short* __restrict__ w2,
                                             const float* __restrict__ b1,
                                             const float* __restrict__ b2,
                                             const float* __restrict__ h,
                                             const float* __restrict__ gamma,
                                             const float* __restrict__ beta,
                                             float* __restrict__ out, int nTiles) {
  __shared__ unsigned short yt[16][LDSW];
  __shared__ float lnp[16][4][2];
  const int wave = threadIdx.x >> 6;
  const int l = threadIdx.x & 63;
  const int row0 = blockIdx.x * 16;
  const int lr = l & 15;
  const int lq = l >> 4;

  // prefetch: h residual (8 scalar f32) + epilogue params; latency hides under MFMAs
  float hres[2][4];
#pragma unroll
  for (int j = 0; j < 2; ++j) {
    const int cc = (wave * 2 + j) * 16 + lr;
#pragma unroll
    for (int r = 0; r < 4; ++r)
      hres[j][r] = h[(size_t)(row0 + lq * 4 + r) * HID + cc];
  }
  float bs1[2], bs2[2], gg[2], bb[2];
#pragma unroll
  for (int j = 0; j < 2; ++j) {
    const int cc = (wave * 2 + j) * 16 + lr;
    bs1[j] = b1[cc]; bs2[j] = b2[cc]; gg[j] = gamma[cc]; bb[j] = beta[cc];
  }

  bf16x8 a[4];
#pragma unroll
  for (int ks = 0; ks < 4; ++ks)
    a[ks] = *reinterpret_cast<const bf16x8*>(zbf + (size_t)(row0 + lr) * HID + ks * 32 + lq * 8);

  f32x4 acc[2];
#pragma unroll
  for (int j = 0; j < 2; ++j) acc[j] = (f32x4){0.f, 0.f, 0.f, 0.f};
#pragma unroll
  for (int j = 0; j < 2; ++j) {
    const unsigned short* wb = w1 + (size_t)((wave * 2 + j) * 16 + lr) * HID + lq * 8;
#pragma unroll
    for (int ks = 0; ks < 4; ++ks) {
      const bf16x8 b = *reinterpret_cast<const bf16x8*>(wb + ks * 32);
      acc[j] = __builtin_amdgcn_mfma_f32_16x16x32_bf16(a[ks], b, acc[j], 0, 0, 0);
    }
  }

#pragma unroll
  for (int j = 0; j < 2; ++j) {
    const int cc = (wave * 2 + j) * 16 + lr;
#pragma unroll
    for (int r = 0; r < 4; ++r)
      yt[lq * 4 + r][cc] = f2bf(fmaxf(acc[j][r] + bs1[j], 0.f));
  }
  __syncthreads();

  bf16x8 a2[4];
#pragma unroll
  for (int ks = 0; ks < 4; ++ks)
    a2[ks] = *reinterpret_cast<const bf16x8*>(&yt[lr][ks * 32 + lq * 8]);

#pragma unroll
  for (int j = 0; j < 2; ++j) acc[j] = (f32x4){0.f, 0.f, 0.f, 0.f};
#pragma unroll
  for (int j = 0; j < 2; ++j) {
    const unsigned short* wb = w2 + (size_t)((wave * 2 + j) * 16 + lr) * HID + lq * 8;
#pragma unroll
    for (int ks = 0; ks < 4; ++ks) {
      const bf16x8 b = *reinterpret_cast<const bf16x8*>(wb + ks * 32);
      acc[j] = __builtin_amdgcn_mfma_f32_16x16x32_bf16(a2[ks], b, acc[j], 0, 0, 0);
    }
  }

#pragma unroll
  for (int j = 0; j < 2; ++j)
#pragma unroll
    for (int r = 0; r < 4; ++r)
      acc[j][r] += bs2[j] + hres[j][r];

#pragma unroll
  for (int r = 0; r < 4; ++r) {
    float s = acc[0][r] + acc[1][r];
    float ss = acc[0][r] * acc[0][r] + acc[1][r] * acc[1][r];
#pragma unroll
    for (int m = 1; m < 16; m <<= 1) {
      s += __shfl_xor(s, m, 64);
      ss += __shfl_xor(ss, m, 64);
    }
    if (lr == 0) {
      lnp[lq * 4 + r][wave][0] = s;
      lnp[lq * 4 + r][wave][1] = ss;
    }
  }
  __syncthreads();

  float mu_[4], rstd_[4];
#pragma unroll
  for (int r = 0; r < 4; ++r) {
    const int rt = lq * 4 + r;
    float s = 0.f, ss = 0.f;
#pragma unroll
    for (int w = 0; w < 4; ++w) {
      const float2 p = *reinterpret_cast<const float2*>(&lnp[rt][w][0]);
      s += p.x;
      ss += p.y;
    }
    const float mu = s * (1.f / 128.f);
    const float var = ss * (1.f / 128.f) - mu * mu;
    mu_[r] = mu;
    rstd_[r] = rsqrtf(var + LN_EPS);
  }
#pragma unroll
  for (int j = 0; j < 2; ++j) {
    const int cc = (wave * 2 + j) * 16 + lr;
#pragma unroll
    for (int r = 0; r < 4; ++r) {
      const int row = row0 + lq * 4 + r;
      const float o = (acc[j][r] - mu_[r]) * rstd_[r] * gg[j] + bb[j];
      out[(size_t)row * HID + cc] = fmaxf(o, 0.f);
    }
  }
  (void)nTiles;
}

extern "C" void kernel_launch(void* const* d_in, const int* in_sizes, int n_in,
                              void* d_out, int out_size, void* d_ws, size_t ws_size,
                              hipStream_t stream) {
  const float* h     = (const float*)d_in[0];
  const int*   ei    = (const int*)d_in[1];
  const float* W1    = (const float*)d_in[2];
  const float* b1    = (const float*)d_in[3];
  const float* W2    = (const float*)d_in[4];
  const float* b2    = (const float*)d_in[5];
  const float* eps   = (const float*)d_in[6];
  const float* gamma = (const float*)d_in[7];
  const float* beta  = (const float*)d_in[8];

  const int nNodes = in_sizes[0] / HID;     // 50000
  const int nE     = in_sizes[1] / 2;       // 640000
  const int nb     = (nNodes + 255) / 256;  // 196
  const int nh4    = nNodes * HID / 4;      // 1.6M
  const int nw4    = HID * HID / 4;         // 4096

  // ws layout (ints; bf16 regions 16B-aligned):
  // counts[50000] | offsets[50001] | st[196 ull @int 100002, byte 400008 (8-aligned)] |
  // rank @100800 | esrc @740800 | hbf | zbf | w1bf | w2bf
  int* counts  = (int*)d_ws;
  int* offsets = counts + nNodes;                       // @ 50000
  unsigned long long* st = (unsigned long long*)(counts + 100002);
  int* rank    = counts + 100800;                       // byte 403200, 16B-aligned
  int* esrc    = rank + nE;                             // @ 740800
  unsigned short* hbf  = (unsigned short*)(esrc + nE);  // byte 5,523,200
  unsigned short* zbf  = hbf + (size_t)nNodes * HID;    // +12.8 MB
  unsigned short* w1bf = zbf + (size_t)nNodes * HID;    // +12.8 MB
  unsigned short* w2bf = w1bf + HID * HID;              // +32 KB (total ~31.2 MB)

  // one memset zeroes counts AND lookback state (offsets in between: harmless)
  hipMemsetAsync(counts, 0, (size_t)(100002 + 2 * nb) * sizeof(int), stream);

  const int EB = (nE + 255) / 256;          // 2500 edge blocks
  k_cvt_rank<<<EB + 2048, 256, 0, stream>>>(h, W1, W2, (uint2*)hbf, (uint2*)w1bf, (uint2*)w2bf,
                                            nh4, nw4, ei, counts, rank, nE, EB);
  k_scanLB<<<nb, 256, 0, stream>>>(counts, offsets, st, nNodes, nb);
  k_scat<<<EB, 256, 0, stream>>>(ei, rank, offsets, esrc, nE);

  k_gather<<<(nNodes * 32 + 255) / 256, 256, 0, stream>>>(hbf, offsets, esrc, eps, zbf, nNodes);

  const int nTiles = nNodes / 16;            // 3125
  k_mmf<<<nTiles, 256, 0, stream>>>(zbf, w1bf, w2bf, b1, b2, h, gamma, beta,
                                    (float*)d_out, nTiles);
}